// Round 25
// baseline (396.128 us; speedup 1.0000x reference)
//
#include <hip/hip_runtime.h>
#include <math.h>

#define NLAY 2
#define BB 16
#define LL 8192
#define HH 128
#define PP 64
#define CIN 64
#define CHS 64            // scan chunk size; tile = 2 chunks = 128 rows
#define NCH 128           // LL/CHS
#define ROWS (BB*LL)      // 131072

typedef unsigned short u16;
typedef __attribute__((ext_vector_type(8))) short  bf16x8;
typedef __attribute__((ext_vector_type(4))) float  f32x4;

// ---- workspace layout (float offsets) ----
#define OFF_H   0ul               // h fp32 [ROWS][128]
#define OFF_FX  16777216ul        // fx bf16 [ROWS][128]
#define OFF_BU  41943040ul        // bu bf16
#define OFF_EF  50331648ul        // carries at 4..7*EFS; 0..EFS doubles as pool partials (last layer)
#define OFF_PC  51380224ul
#define PCS     49408ul           // per-layer: packs 49152 floats (98304 bf16) + 256 consts
#define EFS     131072ul

// fast gelu: erf via Abramowitz-Stegun 7.1.26 (max err 1.5e-7) + HW exp
__device__ __forceinline__ float gelu_(float x){
  float z = fabsf(x)*0.70710678118654752440f;
  float t = 1.0f/(1.0f + 0.3275911f*z);
  float poly = t*(0.254829592f + t*(-0.284496736f + t*(1.421413741f
             + t*(-1.453152027f + t*1.061405429f))));
  float erfv = 1.0f - poly*__expf(-z*z);
  erfv = copysignf(erfv, x);
  return 0.5f*x*(1.0f + erfv);
}
__device__ __forceinline__ u16 f2bf(float f){
  unsigned int u = __float_as_uint(f);
  return (u16)((u + 0x7fffu + ((u>>16)&1u)) >> 16);
}
__device__ __forceinline__ float bf2f(u16 v){
  return __uint_as_float(((unsigned int)v)<<16);
}

// ================= precompute (parallelized: grid (NLAY,16)) =================
__global__ void k_pre(const float* __restrict__ Lam_re, const float* __restrict__ Lam_im,
                      const float* __restrict__ B_re, const float* __restrict__ B_im,
                      const float* __restrict__ C_re, const float* __restrict__ C_im,
                      const float* __restrict__ W_enc, const float* __restrict__ W_dec,
                      const float* __restrict__ log_step, float* __restrict__ ws)
{
  int i = blockIdx.x, sl = blockIdx.y, tid = threadIdx.x;
  float* pcf = ws + OFF_PC + (unsigned long)i*PCS;
  u16* pb = (u16*)pcf;
  float* cons = pcf + 49152;
  __shared__ float qre[PP], qim[PP];
  if (tid < PP){
    int p = tid;
    float lre = Lam_re[i*PP+p], lim = Lam_im[i*PP+p];
    float st = expf(log_step[i*PP+p]);
    float er = expf(lre*st), ang = lim*st;
    float Lr = er*cosf(ang), Li = er*sinf(ang);
    float wr = Lr - 1.0f, wi = Li;
    float den = lre*lre + lim*lim;
    qre[p] = (wr*lre + wi*lim)/den;
    qim[p] = (wi*lre - wr*lim)/den;
    if (sl == 0){
      cons[p] = Lr; cons[64+p] = Li;
      float ec = expf(lre*st*(float)CHS), ac = lim*st*(float)CHS;
      cons[128+p] = ec*cosf(ac); cons[192+p] = ec*sinf(ac);
    }
  }
  __syncthreads();
  // bu pack
  for (int t0 = sl*1024 + tid; t0 < (sl+1)*1024; t0 += 256){
    int j = t0&7, ln = (t0>>3)&63, ks = (t0>>9)&3, ct = t0>>11;
    int col = ct*16 + (ln&15);
    int k = ks*32 + (ln>>4)*8 + j;
    int cc = col>>6, p = col&63;
    float br = B_re[(i*PP+p)*HH + k], bi = B_im[(i*PP+p)*HH + k];
    pb[t0] = f2bf(cc ? (qre[p]*bi + qim[p]*br) : (qre[p]*br - qim[p]*bi));
  }
  // y pack
  for (int t0 = sl*2048 + tid; t0 < (sl+1)*2048; t0 += 256){
    int j = t0&7, ln = (t0>>3)&63, ks = (t0>>9)&7, ct = t0>>12;
    int hh = ct*16 + (ln&15);
    int k = ks*32 + (ln>>4)*8 + j;
    int blk = k>>6, p = k&63;
    int base = (i*HH + hh)*(2*PP);
    float v = (blk==0)? C_re[base+p] : (blk==1)? -C_im[base+p]
            : (blk==2)? C_re[base+PP+p] : -C_im[base+PP+p];
    pb[16384 + t0] = f2bf(v);
  }
  // enc pack
  for (int t0 = sl*2048 + tid; t0 < (sl+1)*2048; t0 += 256){
    int j = t0&7, ln = (t0>>3)&63, ks = (t0>>9)&3, ct = t0>>11;
    int colj = (ct<8) ? ct*16 + (ln&15) : 128 + (ct-8)*16 + (ln&15);
    int k = ks*32 + (ln>>4)*8 + j;
    pb[49152 + t0] = f2bf(W_enc[((long)i*HH + k)*(2*HH) + colj]);
  }
  // dec pack
  for (int t0 = sl*1024 + tid; t0 < (sl+1)*1024; t0 += 256){
    int j = t0&7, ln = (t0>>3)&63, ks = (t0>>9)&3, ct = t0>>11;
    int col = ct*16 + (ln&15);
    int k = ks*32 + (ln>>4)*8 + j;
    pb[81920 + t0] = f2bf(W_dec[((long)i*HH + k)*HH + col]);
  }
}

// ================= helpers for 128-row tiles =================
#define LDS_TO_GLOBAL128(SRCLDS, DST) do{ \
  _Pragma("unroll") \
  for (int rep=0; rep<8; rep++){ int e = tid + rep*256; \
    int r = e>>4, c8 = (e&15)*8; \
    *(bf16x8*)((DST) + (g0 + r)*HH + c8) = *(const bf16x8*)&(SRCLDS)[r*136 + c8]; } }while(0)

#define GLOBAL_TO_LDS128(DSTLDS, SRC) do{ \
  _Pragma("unroll") \
  for (int rep=0; rep<8; rep++){ int e = tid + rep*256; \
    int r = e>>4, c8 = (e&15)*8; \
    *(bf16x8*)&(DSTLDS)[r*136 + c8] = *(const bf16x8*)((SRC) + (g0 + r)*HH + c8); } }while(0)

// two row-tiles per wave: rows R0+c and R0+16+c
#define MAINLOOP2(LDSA, PACK, ACCA, ACCB, KSTOT, KSOFF) do{ \
  _Pragma("unroll") \
  for (int ks=0; ks<4; ks++){ \
    bf16x8 a0 = *(const bf16x8*)&(LDSA)[(R0 + c)*136 + ks*32 + g*8]; \
    bf16x8 a1 = *(const bf16x8*)&(LDSA)[(R0 + 16 + c)*136 + ks*32 + g*8]; \
    _Pragma("unroll") \
    for (int ct=0; ct<8; ct++){ \
      bf16x8 b = ((const bf16x8*)(PACK))[(ct*(KSTOT) + (KSOFF) + ks)*64 + lane]; \
      ACCA[ct] = __builtin_amdgcn_mfma_f32_16x16x32_bf16(a0, b, ACCA[ct], 0,0,0); \
      ACCB[ct] = __builtin_amdgcn_mfma_f32_16x16x32_bf16(a1, b, ACCB[ct], 0,0,0); } } }while(0)

#define ACC_ZERO2(ACCA, ACCB) \
  f32x4 ACCA[8], ACCB[8]; \
  { f32x4 z = {0.f,0.f,0.f,0.f}; \
    _Pragma("unroll") for (int ct=0; ct<8; ct++){ ACCA[ct]=z; ACCB[ct]=z; } }

// scan reductions from a 128x136 LDS bu tile (all 4 waves: dir=w>>1, chunk=w&1)
#define TILE_SCAN_REDUCE(SB, CONS, WS) do{ \
  int p = lane; int cc = wid & 1; \
  long o = ((long)blockIdx.x*2 + cc)*PP + p; \
  float Lr = (CONS)[p], Li = (CONS)[64+p]; \
  int rb = cc*64; \
  if ((wid>>1) == 0){ \
    float efr=0.f, efi=0.f; \
    _Pragma("unroll 4") \
    for (int i=0;i<CHS;i++){ \
      float br = bf2f((SB)[(rb+i)*136+p]), bi = bf2f((SB)[(rb+i)*136+64+p]); \
      float nr = Lr*efr - Li*efi + br; \
      efi = Lr*efi + Li*efr + bi; efr = nr; \
    } \
    (WS)[OFF_EF + o] = efr;  (WS)[OFF_EF+EFS + o] = efi; \
  } else { \
    float ebr=0.f, ebi=0.f, pwr=1.f, pwi=0.f; \
    _Pragma("unroll 4") \
    for (int i=0;i<CHS;i++){ \
      float br = bf2f((SB)[(rb+i)*136+p]), bi = bf2f((SB)[(rb+i)*136+64+p]); \
      ebr += pwr*br - pwi*bi; \
      ebi += pwr*bi + pwi*br; \
      float tr = pwr*Lr - pwi*Li; \
      pwi = pwr*Li + pwi*Lr; pwr = tr; \
    } \
    (WS)[OFF_EF+2*EFS + o] = ebr;  (WS)[OFF_EF+3*EFS + o] = ebi; \
  } }while(0)

// ================= k_inbus: input proj + h write + LN1 + bu GEMM + scan reductions =================
// thread = (row r = tid&127, col-half hf = tid>>7); W_in reads wave-uniform.
__global__ __launch_bounds__(256,2) void k_inbus(const float* __restrict__ x,
                      const float* __restrict__ W_in, const float* __restrict__ b_in,
                      const float* __restrict__ gam, const float* __restrict__ bta,
                      const u16* __restrict__ pack, float* __restrict__ hout,
                      u16* __restrict__ fxb, u16* __restrict__ bub,
                      const float* __restrict__ cons, float* __restrict__ ws)
{
  __shared__ u16 sA[128*136];   // LN scratch -> fx bf16
  __shared__ u16 sB[128*136];   // x staging (fp32) -> bu bf16
  int tid = threadIdx.x; long g0 = (long)blockIdx.x*128;
  int bb = (int)(g0 / LL); int l0 = (int)(g0 % LL);
  int lane = tid & 63, wid = tid >> 6;
  int g = lane >> 4, c = lane & 15;
  int R0 = wid*32;
  // stage x tile [64 cin][128 l] -> sB as fp32, stride 132 (33792 B <= 34816 B)
  float* sXf = (float*)sB;
  #pragma unroll
  for (int rep=0; rep<32; rep++){
    int e = tid + rep*256; int k = e>>7, l = e&127;
    sXf[k*132 + l] = x[((long)bb*CIN + k)*LL + l0 + l];
  }
  __syncthreads();
  // per-thread row GEMM: h[row r, cols hf*64..+63]
  int r = tid & 127, hf = tid >> 7;
  float acc[64];
  #pragma unroll
  for (int j=0;j<64;j++) acc[j] = b_in[hf*64 + j];
  #pragma unroll 2
  for (int k=0;k<64;k++){
    float a = sXf[k*132 + r];
    const float* wr = W_in + k*HH + hf*64;
    #pragma unroll
    for (int j=0;j<64;j++) acc[j] += a*wr[j];
  }
  // write h (residual input for layer-0 syed); contiguous float4 per thread
  {
    float4* hp = (float4*)(hout + (g0 + r)*HH + hf*64);
    #pragma unroll
    for (int j4=0;j4<16;j4++) hp[j4] = *(float4*)&acc[j4*4];
  }
  // LN1: partner exchange via LDS (sA front as fp32 scratch)
  float sum=0.f, sq=0.f;
  #pragma unroll
  for (int j=0;j<64;j++){ sum += acc[j]; sq += acc[j]*acc[j]; }
  float* sAf = (float*)sA;
  sAf[tid] = sum; sAf[256+tid] = sq;
  __syncthreads();
  float tsum = sAf[tid] + sAf[tid^128];
  float tsq  = sAf[256+tid] + sAf[256+(tid^128)];
  float m = tsum*(1.0f/HH);
  float inv = 1.0f/sqrtf(tsq*(1.0f/HH) - m*m + 1e-5f);
  __syncthreads();   // done reading sAf before fx overwrites sA
  #pragma unroll
  for (int j=0;j<64;j++){
    int col = hf*64 + j;
    sA[r*136 + col] = f2bf((acc[j]-m)*inv*gam[col] + bta[col]);
  }
  __syncthreads();
  LDS_TO_GLOBAL128(sA, fxb);
  // bu GEMM from sA (x staging in sB dead; barriers passed since last read)
  ACC_ZERO2(bc0, bc1)
  MAINLOOP2(sA, pack, bc0, bc1, 4, 0);
  #pragma unroll
  for (int ct=0; ct<8; ct++){ int col = ct*16 + c;
    #pragma unroll
    for (int q=0;q<4;q++){
      sB[(R0 + g*4 + q)*136 + col]      = f2bf(bc0[ct][q]);
      sB[(R0 + 16 + g*4 + q)*136 + col] = f2bf(bc1[ct][q]); } }
  __syncthreads();
  LDS_TO_GLOBAL128(sB, bub);
  TILE_SCAN_REDUCE(sB, cons, ws);
}

// ================= scan B: carry scan over chunks =================
__global__ void k_scanB(const float* __restrict__ cons, float* __restrict__ ws)
{
  __shared__ float sr[NCH*PP], si[NCH*PP];
  int p = threadIdx.x; int b = blockIdx.x, dir = blockIdx.y;
  float Cr = cons[128+p], Ci = cons[192+p];
  long base = (long)b*NCH*PP;
  const float* er_g = ws + OFF_EF + (dir ? 2*EFS : 0ul)  + base;
  const float* ei_g = ws + OFF_EF + (dir ? 3*EFS : EFS)  + base;
  #pragma unroll 4
  for (int ch=0; ch<NCH; ch++){
    sr[ch*PP+p] = er_g[ch*PP+p];
    si[ch*PP+p] = ei_g[ch*PP+p];
  }
  if (dir == 0){
    float Fr=0.f, Fi=0.f;
    float* or_g = ws + OFF_EF + 4*EFS + base;
    float* oi_g = ws + OFF_EF + 5*EFS + base;
    for (int ch=0; ch<NCH; ch++){
      or_g[ch*PP+p] = Fr; oi_g[ch*PP+p] = Fi;
      float er = sr[ch*PP+p], ei = si[ch*PP+p];
      float nr = Cr*Fr - Ci*Fi + er;
      Fi = Cr*Fi + Ci*Fr + ei; Fr = nr;
    }
  } else {
    float Xr=0.f, Xi=0.f;
    float* or_g = ws + OFF_EF + 6*EFS + base;
    float* oi_g = ws + OFF_EF + 7*EFS + base;
    for (int ch=NCH-1; ch>=0; ch--){
      or_g[ch*PP+p] = Xr; oi_g[ch*PP+p] = Xi;
      float er = sr[ch*PP+p], ei = si[ch*PP+p];
      float nr = er + Cr*Xr - Ci*Xi;
      Xi = ei + Cr*Xi + Ci*Xr; Xr = nr;
    }
  }
}

// ================= fused k_syed (+ tail: next-layer bus OR pooling) =================
__global__ __launch_bounds__(256,2) void k_syed(const u16* __restrict__ bub,
                      const u16* __restrict__ fxb, float* __restrict__ h,
                      const float* __restrict__ cons, float* __restrict__ wsw,
                      const u16* __restrict__ packy, const u16* __restrict__ packe,
                      const u16* __restrict__ packd,
                      const float* __restrict__ Dv,
                      const float* __restrict__ fg, const float* __restrict__ fb,
                      const float* __restrict__ og, const float* __restrict__ ob,
                      int do_tail,
                      const float* __restrict__ gam_nx, const float* __restrict__ bta_nx,
                      const u16* __restrict__ packbu_nx, const float* __restrict__ cons_nx)
{
  __shared__ u16 sA[128*136];   // xf -> fx -> t -> fx_next / pool scratch
  __shared__ u16 sB[128*136];   // bu -> xb -> fy -> bu_next
  int tid = threadIdx.x; long g0 = (long)blockIdx.x*128;
  int lane = tid & 63, wid = tid >> 6;
  int g = lane >> 4, c = lane & 15;
  int R0 = wid*32;
  const float* wsc = wsw;
  GLOBAL_TO_LDS128(sB, bub);
  __syncthreads();
  // fwd scans: waves 0,1 on chunks 0,1: sB(bu) -> sA(xf)
  if (wid < 2){
    int p = lane; int cc = wid;
    float Lr = cons[p], Li = cons[64+p];
    long o = ((long)blockIdx.x*2 + cc)*PP + p;
    float xr = wsc[OFF_EF+4*EFS + o], xi = wsc[OFF_EF+5*EFS + o];
    int rb = cc*64;
    #pragma unroll 4
    for (int i=0;i<CHS;i++){
      float br = bf2f(sB[(rb+i)*136+p]), bi = bf2f(sB[(rb+i)*136+64+p]);
      float nr = Lr*xr - Li*xi + br;
      xi = Lr*xi + Li*xr + bi; xr = nr;
      sA[(rb+i)*136+p] = f2bf(xr); sA[(rb+i)*136+64+p] = f2bf(xi);
    }
  }
  __syncthreads();
  ACC_ZERO2(fy0, fy1)
  MAINLOOP2(sA, packy, fy0, fy1, 8, 0);
  __syncthreads();   // sA(xf) fully consumed
  // bwd scans: waves 2,3 IN-PLACE over sB; everyone stages fx -> sA
  if (wid >= 2){
    int p = lane; int cc = wid - 2;
    float Lr = cons[p], Li = cons[64+p];
    long o = ((long)blockIdx.x*2 + cc)*PP + p;
    float yr = wsc[OFF_EF+6*EFS + o], yi = wsc[OFF_EF+7*EFS + o];
    int rb = cc*64;
    #pragma unroll 4
    for (int i=CHS-1;i>=0;i--){
      float br = bf2f(sB[(rb+i)*136+p]), bi = bf2f(sB[(rb+i)*136+64+p]);
      float nr = Lr*yr - Li*yi + br;
      yi = Lr*yi + Li*yr + bi; yr = nr;
      sB[(rb+i)*136+p] = f2bf(yr); sB[(rb+i)*136+64+p] = f2bf(yi);
    }
  }
  GLOBAL_TO_LDS128(sA, fxb);
  __syncthreads();
  MAINLOOP2(sB, packy, fy0, fy1, 8, 4);
  // a = gelu(y + D*fx) + fx
  #define YEPI2(ACC, RT) \
    _Pragma("unroll") for (int ct=0; ct<8; ct++){ int col = ct*16 + c; \
      float dvc = Dv[col]; \
      _Pragma("unroll") for (int q=0;q<4;q++){ \
        int rowL = R0 + (RT)*16 + g*4 + q; \
        float fxv = bf2f(sA[rowL*136 + col]); \
        ACC[ct][q] = gelu_(ACC[ct][q] + dvc*fxv) + fxv; } }
  YEPI2(fy0, 0)
  YEPI2(fy1, 1)
  // LN2 -> fy bf16 into sB own rows
  #define YLN2(ACC, RT) \
    _Pragma("unroll") for (int q=0;q<4;q++){ \
      float sm=0.f, sq=0.f; \
      _Pragma("unroll") for (int ct=0;ct<8;ct++){ float v=ACC[ct][q]; sm+=v; sq+=v*v; } \
      sm += __shfl_xor(sm,1); sq += __shfl_xor(sq,1); \
      sm += __shfl_xor(sm,2); sq += __shfl_xor(sq,2); \
      sm += __shfl_xor(sm,4); sq += __shfl_xor(sq,4); \
      sm += __shfl_xor(sm,8); sq += __shfl_xor(sq,8); \
      float m = sm*(1.0f/HH); \
      float inv = 1.0f/sqrtf(sq*(1.0f/HH) - m*m + 1e-5f); \
      int rowL = R0 + (RT)*16 + g*4 + q; \
      _Pragma("unroll") for (int ct=0;ct<8;ct++){ int col = ct*16 + c; \
        sB[rowL*136 + col] = f2bf((ACC[ct][q]-m)*inv*fg[col] + fb[col]); } }
  YLN2(fy0, 0)
  YLN2(fy1, 1)
  // enc: A-frags from sB(fy) own rows; t -> sA own rows
  bf16x8 af0[4], af1[4];
  #pragma unroll
  for (int ks=0; ks<4; ks++){
    af0[ks] = *(const bf16x8*)&sB[(R0 + c)*136 + ks*32 + g*8];
    af1[ks] = *(const bf16x8*)&sB[(R0 + 16 + c)*136 + ks*32 + g*8];
  }
  #pragma unroll
  for (int ct=0; ct<8; ct++){
    f32x4 z = {0.f,0.f,0.f,0.f};
    f32x4 av0=z, av1=z, ag0=z, ag1=z;
    #pragma unroll
    for (int ks=0; ks<4; ks++){
      bf16x8 bv = ((const bf16x8*)packe)[(ct*4 + ks)*64 + lane];
      bf16x8 bg = ((const bf16x8*)packe)[((ct+8)*4 + ks)*64 + lane];
      av0 = __builtin_amdgcn_mfma_f32_16x16x32_bf16(af0[ks], bv, av0, 0,0,0);
      av1 = __builtin_amdgcn_mfma_f32_16x16x32_bf16(af1[ks], bv, av1, 0,0,0);
      ag0 = __builtin_amdgcn_mfma_f32_16x16x32_bf16(af0[ks], bg, ag0, 0,0,0);
      ag1 = __builtin_amdgcn_mfma_f32_16x16x32_bf16(af1[ks], bg, ag1, 0,0,0);
    }
    #pragma unroll
    for (int q=0;q<4;q++){
      sA[(R0 + g*4 + q)*136 + ct*16 + c]      = f2bf(av0[q]*gelu_(ag0[q]));
      sA[(R0 + 16 + g*4 + q)*136 + ct*16 + c] = f2bf(av1[q]*gelu_(ag1[q]));
    }
  }
  // dec GEMM
  ACC_ZERO2(ad0, ad1)
  MAINLOOP2(sA, packd, ad0, ad1, 4, 0);
  // blk + fy(sB) + h residual; LN3 -> AD (h write deferred to tails)
  #define DADD2(AD, RT) \
    _Pragma("unroll") for (int ct=0; ct<8; ct++){ int col = ct*16 + c; \
      _Pragma("unroll") for (int q=0;q<4;q++){ \
        int rowL = R0 + (RT)*16 + g*4 + q; long ix = (g0+rowL)*HH + col; \
        AD[ct][q] += bf2f(sB[rowL*136 + col]) + h[ix]; } }
  DADD2(ad0, 0)
  DADD2(ad1, 1)
  #define DLN2(AD, RT) \
    _Pragma("unroll") for (int q=0;q<4;q++){ \
      float sm=0.f, sq=0.f; \
      _Pragma("unroll") for (int ct=0;ct<8;ct++){ float v=AD[ct][q]; sm+=v; sq+=v*v; } \
      sm += __shfl_xor(sm,1); sq += __shfl_xor(sq,1); \
      sm += __shfl_xor(sm,2); sq += __shfl_xor(sq,2); \
      sm += __shfl_xor(sm,4); sq += __shfl_xor(sq,4); \
      sm += __shfl_xor(sm,8); sq += __shfl_xor(sq,8); \
      float m = sm*(1.0f/HH); \
      float inv = 1.0f/sqrtf(sq*(1.0f/HH) - m*m + 1e-5f); \
      int rowL = R0 + (RT)*16 + g*4 + q; (void)rowL; \
      _Pragma("unroll") for (int ct=0;ct<8;ct++){ int col = ct*16 + c; \
        AD[ct][q] = (AD[ct][q]-m)*inv*og[col] + ob[col]; } }
  DLN2(ad0, 0)
  DLN2(ad1, 1)
  if (do_tail){
    // write h (needed by next layer's residual)
    #pragma unroll
    for (int ct=0; ct<8; ct++){ int col = ct*16 + c;
      #pragma unroll
      for (int q=0;q<4;q++){
        h[(g0 + R0 + g*4 + q)*HH + col]      = ad0[ct][q];
        h[(g0 + R0 + 16 + g*4 + q)*HH + col] = ad1[ct][q]; } }
    // next-layer LN1 on register h; fx -> sA own rows
    #define TLN(AD, RT) \
      _Pragma("unroll") for (int q=0;q<4;q++){ \
        float sm=0.f, sq=0.f; \
        _Pragma("unroll") for (int ct=0;ct<8;ct++){ float v=AD[ct][q]; sm+=v; sq+=v*v; } \
        sm += __shfl_xor(sm,1); sq += __shfl_xor(sq,1); \
        sm += __shfl_xor(sm,2); sq += __shfl_xor(sq,2); \
        sm += __shfl_xor(sm,4); sq += __shfl_xor(sq,4); \
        sm += __shfl_xor(sm,8); sq += __shfl_xor(sq,8); \
        float m = sm*(1.0f/HH); \
        float inv = 1.0f/sqrtf(sq*(1.0f/HH) - m*m + 1e-5f); \
        int rowL = R0 + (RT)*16 + g*4 + q; \
        _Pragma("unroll") for (int ct=0;ct<8;ct++){ int col = ct*16 + c; \
          sA[rowL*136 + col] = f2bf((AD[ct][q]-m)*inv*gam_nx[col] + bta_nx[col]); } }
    TLN(ad0, 0)
    TLN(ad1, 1)
    __syncthreads();
    LDS_TO_GLOBAL128(sA, (u16*)fxb);
    ACC_ZERO2(bc0, bc1)
    MAINLOOP2(sA, packbu_nx, bc0, bc1, 4, 0);
    #pragma unroll
    for (int ct=0; ct<8; ct++){ int col = ct*16 + c;
      #pragma unroll
      for (int q=0;q<4;q++){
        sB[(R0 + g*4 + q)*136 + col]      = f2bf(bc0[ct][q]);
        sB[(R0 + 16 + g*4 + q)*136 + col] = f2bf(bc1[ct][q]); } }
    __syncthreads();
    LDS_TO_GLOBAL128(sB, (u16*)bub);
    TILE_SCAN_REDUCE(sB, cons_nx, wsw);
  } else {
    // last layer: fused mean-pool partials (skip h write entirely)
    float* sAf = (float*)sA;   // 512-float scratch (sA dead)
    float ps[8];
    #pragma unroll
    for (int ct=0; ct<8; ct++){
      float s8 = 0.f;
      #pragma unroll
      for (int q=0;q<4;q++) s8 += ad0[ct][q] + ad1[ct][q];
      s8 += __shfl_xor(s8, 16);
      s8 += __shfl_xor(s8, 32);
      ps[ct] = s8;
    }
    __syncthreads();
    if ((lane>>4) == 0){
      #pragma unroll
      for (int ct=0; ct<8; ct++)
        sAf[wid*128 + ct*16 + c] = ps[ct];
    }
    __syncthreads();
    if (tid < 128){
      float tot = sAf[tid] + sAf[128+tid] + sAf[256+tid] + sAf[384+tid];
      wsw[OFF_EF + (long)blockIdx.x*HH + tid] = tot;
    }
  }
}

// ================= classifier head (fp32 out); pooled from per-block partials =================
__global__ void k_cls(const float* __restrict__ part, const float* __restrict__ Wc1,
                      const float* __restrict__ bc1, const float* __restrict__ Wc2,
                      const float* __restrict__ bc2, float* __restrict__ out)
{
  __shared__ float pooled[BB*HH];
  __shared__ float zs[BB*64];
  int tid = threadIdx.x;
  for (int k=0;k<8;k++){
    int e = tid + k*256; int b = e>>7, hh = e&127;
    float s = 0.f;
    for (int seg=0; seg<64; seg++) s += part[((long)b*64 + seg)*HH + hh];
    pooled[e] = s * (1.0f/(float)LL);
  }
  __syncthreads();
  for (int k=0;k<4;k++){
    int e = tid + k*256; int b = e>>6, j = e&63;
    float s = bc1[j];
    for (int hh=0; hh<HH; hh++) s += pooled[b*HH+hh]*Wc1[hh*64+j];
    zs[e] = fmaxf(s, 0.0f);
  }
  __syncthreads();
  if (tid < BB*3){
    int b = tid/3, cc = tid%3;
    float s = bc2[cc];
    for (int j=0;j<64;j++) s += zs[b*64+j]*Wc2[j*3+cc];
    out[tid] = s;
  }
}

extern "C" void kernel_launch(void* const* d_in, const int* in_sizes, int n_in,
                              void* d_out, int out_size, void* d_ws, size_t ws_size,
                              hipStream_t stream) {
  const float* x       = (const float*)d_in[0];
  const float* W_in    = (const float*)d_in[1];
  const float* b_in    = (const float*)d_in[2];
  const float* attn_g  = (const float*)d_in[3];
  const float* attn_b  = (const float*)d_in[4];
  const float* Lam_re  = (const float*)d_in[5];
  const float* Lam_im  = (const float*)d_in[6];
  const float* B_re    = (const float*)d_in[7];
  const float* B_im    = (const float*)d_in[8];
  const float* C_re    = (const float*)d_in[9];
  const float* C_im    = (const float*)d_in[10];
  const float* Dv      = (const float*)d_in[11];
  const float* log_step= (const float*)d_in[12];
  const float* ff_g    = (const float*)d_in[13];
  const float* ff_b    = (const float*)d_in[14];
  const float* W_enc   = (const float*)d_in[15];
  const float* W_dec   = (const float*)d_in[16];
  const float* out_g   = (const float*)d_in[17];
  const float* out_b   = (const float*)d_in[18];
  const float* Wc1     = (const float*)d_in[19];
  const float* bc1     = (const float*)d_in[20];
  const float* Wc2     = (const float*)d_in[21];
  const float* bc2     = (const float*)d_in[22];
  float* ws = (float*)d_ws;

  float* hbuf = ws + OFF_H;
  u16* fxb = (u16*)(ws + OFF_FX);
  u16* bub = (u16*)(ws + OFF_BU);

  k_pre<<<dim3(NLAY,16), 256, 0, stream>>>(Lam_re, Lam_im, B_re, B_im, C_re, C_im,
                                           W_enc, W_dec, log_step, ws);
  // fused input-proj + layer-0 bus
  {
    const u16* pk0 = (const u16*)(ws + OFF_PC);
    const float* cons0 = ws + OFF_PC + 49152;
    k_inbus<<<ROWS/128, 256, 0, stream>>>(x, W_in, b_in, attn_g, attn_b, pk0,
                                          hbuf, fxb, bub, cons0, ws);
  }
  for (int i=0;i<NLAY;i++){
    const u16* pk = (const u16*)(ws + OFF_PC + (unsigned long)i*PCS);
    const float* cons = ws + OFF_PC + (unsigned long)i*PCS + 49152;
    int nx = i+1;
    const u16* pk_nx = (const u16*)(ws + OFF_PC + (unsigned long)(nx % NLAY)*PCS);
    const float* cons_nx = ws + OFF_PC + (unsigned long)(nx % NLAY)*PCS + 49152;
    int do_tail = (nx < NLAY) ? 1 : 0;
    k_scanB<<<dim3(BB,2), 64, 0, stream>>>(cons, ws);
    k_syed<<<ROWS/128, 256, 0, stream>>>(bub, fxb, hbuf, cons, ws,
                                         pk + 16384, pk + 49152, pk + 81920,
                                         Dv+i*HH, ff_g+i*HH, ff_b+i*HH,
                                         out_g+i*HH, out_b+i*HH,
                                         do_tail,
                                         attn_g + (nx % NLAY)*HH, attn_b + (nx % NLAY)*HH,
                                         pk_nx, cons_nx);
  }
  k_cls<<<1, 256, 0, stream>>>(ws + OFF_EF, Wc1, bc1, Wc2, bc2, (float*)d_out);
}

// Round 26
// 334.604 us; speedup vs baseline: 1.1839x; 1.1839x over previous
//
#include <hip/hip_runtime.h>
#include <math.h>

#define NLAY 2
#define BB 16
#define LL 8192
#define HH 128
#define PP 64
#define CIN 64
#define CHS 64            // scan chunk size; tile = 2 chunks = 128 rows
#define NCH 128           // LL/CHS
#define ROWS (BB*LL)      // 131072

typedef unsigned short u16;
typedef __attribute__((ext_vector_type(8))) short  bf16x8;
typedef __attribute__((ext_vector_type(4))) float  f32x4;

// ---- workspace layout (float offsets) ----
#define OFF_H   0ul               // h fp32 [ROWS][128]
#define OFF_FX  16777216ul        // fx bf16 [ROWS][128]
#define OFF_BU  41943040ul        // bu bf16
#define OFF_EF  50331648ul        // carries at 4..7*EFS; 0..EFS doubles as pool partials (last layer)
#define OFF_PC  51380224ul
#define PCS     49408ul           // per-layer: packs 49152 floats (98304 bf16) + 256 consts
#define EFS     131072ul

// fast gelu: erf via Abramowitz-Stegun 7.1.26 (max err 1.5e-7) + HW exp
__device__ __forceinline__ float gelu_(float x){
  float z = fabsf(x)*0.70710678118654752440f;
  float t = 1.0f/(1.0f + 0.3275911f*z);
  float poly = t*(0.254829592f + t*(-0.284496736f + t*(1.421413741f
             + t*(-1.453152027f + t*1.061405429f))));
  float erfv = 1.0f - poly*__expf(-z*z);
  erfv = copysignf(erfv, x);
  return 0.5f*x*(1.0f + erfv);
}
__device__ __forceinline__ u16 f2bf(float f){
  unsigned int u = __float_as_uint(f);
  return (u16)((u + 0x7fffu + ((u>>16)&1u)) >> 16);
}
__device__ __forceinline__ float bf2f(u16 v){
  return __uint_as_float(((unsigned int)v)<<16);
}

// ================= precompute (parallelized: grid (NLAY,16)) =================
__global__ void k_pre(const float* __restrict__ Lam_re, const float* __restrict__ Lam_im,
                      const float* __restrict__ B_re, const float* __restrict__ B_im,
                      const float* __restrict__ C_re, const float* __restrict__ C_im,
                      const float* __restrict__ W_enc, const float* __restrict__ W_dec,
                      const float* __restrict__ log_step, float* __restrict__ ws)
{
  int i = blockIdx.x, sl = blockIdx.y, tid = threadIdx.x;
  float* pcf = ws + OFF_PC + (unsigned long)i*PCS;
  u16* pb = (u16*)pcf;
  float* cons = pcf + 49152;
  __shared__ float qre[PP], qim[PP];
  if (tid < PP){
    int p = tid;
    float lre = Lam_re[i*PP+p], lim = Lam_im[i*PP+p];
    float st = expf(log_step[i*PP+p]);
    float er = expf(lre*st), ang = lim*st;
    float Lr = er*cosf(ang), Li = er*sinf(ang);
    float wr = Lr - 1.0f, wi = Li;
    float den = lre*lre + lim*lim;
    qre[p] = (wr*lre + wi*lim)/den;
    qim[p] = (wi*lre - wr*lim)/den;
    if (sl == 0){
      cons[p] = Lr; cons[64+p] = Li;
      float ec = expf(lre*st*(float)CHS), ac = lim*st*(float)CHS;
      cons[128+p] = ec*cosf(ac); cons[192+p] = ec*sinf(ac);
    }
  }
  __syncthreads();
  // bu pack
  for (int t0 = sl*1024 + tid; t0 < (sl+1)*1024; t0 += 256){
    int j = t0&7, ln = (t0>>3)&63, ks = (t0>>9)&3, ct = t0>>11;
    int col = ct*16 + (ln&15);
    int k = ks*32 + (ln>>4)*8 + j;
    int cc = col>>6, p = col&63;
    float br = B_re[(i*PP+p)*HH + k], bi = B_im[(i*PP+p)*HH + k];
    pb[t0] = f2bf(cc ? (qre[p]*bi + qim[p]*br) : (qre[p]*br - qim[p]*bi));
  }
  // y pack
  for (int t0 = sl*2048 + tid; t0 < (sl+1)*2048; t0 += 256){
    int j = t0&7, ln = (t0>>3)&63, ks = (t0>>9)&7, ct = t0>>12;
    int hh = ct*16 + (ln&15);
    int k = ks*32 + (ln>>4)*8 + j;
    int blk = k>>6, p = k&63;
    int base = (i*HH + hh)*(2*PP);
    float v = (blk==0)? C_re[base+p] : (blk==1)? -C_im[base+p]
            : (blk==2)? C_re[base+PP+p] : -C_im[base+PP+p];
    pb[16384 + t0] = f2bf(v);
  }
  // enc pack
  for (int t0 = sl*2048 + tid; t0 < (sl+1)*2048; t0 += 256){
    int j = t0&7, ln = (t0>>3)&63, ks = (t0>>9)&3, ct = t0>>11;
    int colj = (ct<8) ? ct*16 + (ln&15) : 128 + (ct-8)*16 + (ln&15);
    int k = ks*32 + (ln>>4)*8 + j;
    pb[49152 + t0] = f2bf(W_enc[((long)i*HH + k)*(2*HH) + colj]);
  }
  // dec pack
  for (int t0 = sl*1024 + tid; t0 < (sl+1)*1024; t0 += 256){
    int j = t0&7, ln = (t0>>3)&63, ks = (t0>>9)&3, ct = t0>>11;
    int col = ct*16 + (ln&15);
    int k = ks*32 + (ln>>4)*8 + j;
    pb[81920 + t0] = f2bf(W_dec[((long)i*HH + k)*HH + col]);
  }
}

// ================= input projection (fp32 VALU) =================
#define WRITEOUT32(ARR, COLBASE, DST) \
  __syncthreads(); \
  _Pragma("unroll") \
  for (int jj=0;jj<32;jj++) s[tid*33+jj] = ARR[jj]; \
  __syncthreads(); \
  _Pragma("unroll") \
  for (int k2=0;k2<32;k2++){ int e = tid + k2*256; int r = e>>5, jj = e&31; \
    (DST)[(g0+(long)r)*HH + (COLBASE) + jj] = s[r*33+jj]; }

__global__ __launch_bounds__(256,2) void k_inproj(const float* __restrict__ x,
                         const float* __restrict__ W_in,
                         const float* __restrict__ b_in, float* __restrict__ hout)
{
  __shared__ float s[256*33];
  int tid = threadIdx.x;
  int b = blockIdx.y;
  int l0 = blockIdx.x*256;
  long g0 = (long)b*LL + l0;
  float c0[32], c1[32], c2[32], c3[32];
  #pragma unroll
  for (int j=0;j<32;j++){ c0[j]=b_in[j]; c1[j]=b_in[32+j]; c2[j]=b_in[64+j]; c3[j]=b_in[96+j]; }
  #define INP_CHUNK(KC) { \
    __syncthreads(); \
    _Pragma("unroll") \
    for (int k2=0;k2<32;k2++){ \
      s[tid*33+k2] = x[((long)b*CIN + (KC)*32+k2)*LL + l0 + tid]; } \
    __syncthreads(); \
    _Pragma("unroll 2") \
    for (int kk=0;kk<32;kk++){ \
      float a = s[tid*33+kk]; \
      const float* wr = W_in + ((KC)*32+kk)*HH; \
      _Pragma("unroll") \
      for (int j=0;j<32;j++){ c0[j]+=a*wr[j]; c1[j]+=a*wr[32+j]; c2[j]+=a*wr[64+j]; c3[j]+=a*wr[96+j]; } \
    } }
  INP_CHUNK(0) INP_CHUNK(1)
  WRITEOUT32(c0, 0, hout)
  WRITEOUT32(c1, 32, hout)
  WRITEOUT32(c2, 64, hout)
  WRITEOUT32(c3, 96, hout)
}

// ================= helpers for 128-row tiles =================
#define LDS_TO_GLOBAL128(SRCLDS, DST) do{ \
  _Pragma("unroll") \
  for (int rep=0; rep<8; rep++){ int e = tid + rep*256; \
    int r = e>>4, c8 = (e&15)*8; \
    *(bf16x8*)((DST) + (g0 + r)*HH + c8) = *(const bf16x8*)&(SRCLDS)[r*136 + c8]; } }while(0)

#define GLOBAL_TO_LDS128(DSTLDS, SRC) do{ \
  _Pragma("unroll") \
  for (int rep=0; rep<8; rep++){ int e = tid + rep*256; \
    int r = e>>4, c8 = (e&15)*8; \
    *(bf16x8*)&(DSTLDS)[r*136 + c8] = *(const bf16x8*)((SRC) + (g0 + r)*HH + c8); } }while(0)

// two row-tiles per wave: rows R0+c and R0+16+c
#define MAINLOOP2(LDSA, PACK, ACCA, ACCB, KSTOT, KSOFF) do{ \
  _Pragma("unroll") \
  for (int ks=0; ks<4; ks++){ \
    bf16x8 a0 = *(const bf16x8*)&(LDSA)[(R0 + c)*136 + ks*32 + g*8]; \
    bf16x8 a1 = *(const bf16x8*)&(LDSA)[(R0 + 16 + c)*136 + ks*32 + g*8]; \
    _Pragma("unroll") \
    for (int ct=0; ct<8; ct++){ \
      bf16x8 b = ((const bf16x8*)(PACK))[(ct*(KSTOT) + (KSOFF) + ks)*64 + lane]; \
      ACCA[ct] = __builtin_amdgcn_mfma_f32_16x16x32_bf16(a0, b, ACCA[ct], 0,0,0); \
      ACCB[ct] = __builtin_amdgcn_mfma_f32_16x16x32_bf16(a1, b, ACCB[ct], 0,0,0); } } }while(0)

#define ACC_ZERO2(ACCA, ACCB) \
  f32x4 ACCA[8], ACCB[8]; \
  { f32x4 z = {0.f,0.f,0.f,0.f}; \
    _Pragma("unroll") for (int ct=0; ct<8; ct++){ ACCA[ct]=z; ACCB[ct]=z; } }

// scan reductions from a 128x136 LDS bu tile (all 4 waves: dir=w>>1, chunk=w&1)
#define TILE_SCAN_REDUCE(SB, CONS, WS) do{ \
  int p = lane; int cc = wid & 1; \
  long o = ((long)blockIdx.x*2 + cc)*PP + p; \
  float Lr = (CONS)[p], Li = (CONS)[64+p]; \
  int rb = cc*64; \
  if ((wid>>1) == 0){ \
    float efr=0.f, efi=0.f; \
    _Pragma("unroll 4") \
    for (int i=0;i<CHS;i++){ \
      float br = bf2f((SB)[(rb+i)*136+p]), bi = bf2f((SB)[(rb+i)*136+64+p]); \
      float nr = Lr*efr - Li*efi + br; \
      efi = Lr*efi + Li*efr + bi; efr = nr; \
    } \
    (WS)[OFF_EF + o] = efr;  (WS)[OFF_EF+EFS + o] = efi; \
  } else { \
    float ebr=0.f, ebi=0.f, pwr=1.f, pwi=0.f; \
    _Pragma("unroll 4") \
    for (int i=0;i<CHS;i++){ \
      float br = bf2f((SB)[(rb+i)*136+p]), bi = bf2f((SB)[(rb+i)*136+64+p]); \
      ebr += pwr*br - pwi*bi; \
      ebi += pwr*bi + pwi*br; \
      float tr = pwr*Lr - pwi*Li; \
      pwi = pwr*Li + pwi*Lr; pwr = tr; \
    } \
    (WS)[OFF_EF+2*EFS + o] = ebr;  (WS)[OFF_EF+3*EFS + o] = ebi; \
  } }while(0)

// ================= k_bus: LN1 + bu GEMM + chunk scan reductions (layer 0 only) =================
__global__ __launch_bounds__(256,2) void k_bus(const float* __restrict__ h,
                      const float* __restrict__ gam, const float* __restrict__ bta,
                      const u16* __restrict__ pack, u16* __restrict__ fxb,
                      u16* __restrict__ bub, const float* __restrict__ cons,
                      float* __restrict__ ws)
{
  __shared__ u16 sA[128*136];   // fx bf16
  __shared__ u16 sB[128*136];   // bu bf16
  int tid = threadIdx.x; long g0 = (long)blockIdx.x*128;
  int lane = tid & 63, wid = tid >> 6;
  int g = lane >> 4, c = lane & 15;
  int R0 = wid*32;
  #pragma unroll
  for (int rr=0; rr<2; rr++){
    int r = rr*64 + (tid>>2), seg = tid&3;
    float hv[32];
    const float* hp = h + (g0 + r)*HH + seg*32;
    #pragma unroll
    for (int j4=0;j4<8;j4++) *(float4*)&hv[j4*4] = *(const float4*)(hp + j4*4);
    float sum=0.f, sq=0.f;
    #pragma unroll
    for (int j=0;j<32;j++){ sum += hv[j]; sq += hv[j]*hv[j]; }
    sum += __shfl_xor(sum,1); sq += __shfl_xor(sq,1);
    sum += __shfl_xor(sum,2); sq += __shfl_xor(sq,2);
    float m = sum*(1.0f/HH);
    float inv = 1.0f/sqrtf(sq*(1.0f/HH) - m*m + 1e-5f);
    #pragma unroll
    for (int j=0;j<32;j++){
      int col = seg*32 + j;
      sA[r*136 + col] = f2bf((hv[j]-m)*inv*gam[col] + bta[col]);
    }
  }
  __syncthreads();
  LDS_TO_GLOBAL128(sA, fxb);
  ACC_ZERO2(acc0, acc1)
  MAINLOOP2(sA, pack, acc0, acc1, 4, 0);
  #pragma unroll
  for (int ct=0; ct<8; ct++){ int col = ct*16 + c;
    #pragma unroll
    for (int q=0;q<4;q++){
      sB[(R0 + g*4 + q)*136 + col]      = f2bf(acc0[ct][q]);
      sB[(R0 + 16 + g*4 + q)*136 + col] = f2bf(acc1[ct][q]); } }
  __syncthreads();
  LDS_TO_GLOBAL128(sB, bub);
  TILE_SCAN_REDUCE(sB, cons, ws);
}

// ================= scan B: carry scan over chunks =================
__global__ void k_scanB(const float* __restrict__ cons, float* __restrict__ ws)
{
  __shared__ float sr[NCH*PP], si[NCH*PP];
  int p = threadIdx.x; int b = blockIdx.x, dir = blockIdx.y;
  float Cr = cons[128+p], Ci = cons[192+p];
  long base = (long)b*NCH*PP;
  const float* er_g = ws + OFF_EF + (dir ? 2*EFS : 0ul)  + base;
  const float* ei_g = ws + OFF_EF + (dir ? 3*EFS : EFS)  + base;
  #pragma unroll 4
  for (int ch=0; ch<NCH; ch++){
    sr[ch*PP+p] = er_g[ch*PP+p];
    si[ch*PP+p] = ei_g[ch*PP+p];
  }
  if (dir == 0){
    float Fr=0.f, Fi=0.f;
    float* or_g = ws + OFF_EF + 4*EFS + base;
    float* oi_g = ws + OFF_EF + 5*EFS + base;
    for (int ch=0; ch<NCH; ch++){
      or_g[ch*PP+p] = Fr; oi_g[ch*PP+p] = Fi;
      float er = sr[ch*PP+p], ei = si[ch*PP+p];
      float nr = Cr*Fr - Ci*Fi + er;
      Fi = Cr*Fi + Ci*Fr + ei; Fr = nr;
    }
  } else {
    float Xr=0.f, Xi=0.f;
    float* or_g = ws + OFF_EF + 6*EFS + base;
    float* oi_g = ws + OFF_EF + 7*EFS + base;
    for (int ch=NCH-1; ch>=0; ch--){
      or_g[ch*PP+p] = Xr; oi_g[ch*PP+p] = Xi;
      float er = sr[ch*PP+p], ei = si[ch*PP+p];
      float nr = er + Cr*Xr - Ci*Xi;
      Xi = ei + Cr*Xi + Ci*Xr; Xr = nr;
    }
  }
}

// ================= fused k_syed (+ tail: next-layer bus OR pooling) =================
__global__ __launch_bounds__(256,2) void k_syed(const u16* __restrict__ bub,
                      const u16* __restrict__ fxb, float* __restrict__ h,
                      const float* __restrict__ cons, float* __restrict__ wsw,
                      const u16* __restrict__ packy, const u16* __restrict__ packe,
                      const u16* __restrict__ packd,
                      const float* __restrict__ Dv,
                      const float* __restrict__ fg, const float* __restrict__ fb,
                      const float* __restrict__ og, const float* __restrict__ ob,
                      int do_tail,
                      const float* __restrict__ gam_nx, const float* __restrict__ bta_nx,
                      const u16* __restrict__ packbu_nx, const float* __restrict__ cons_nx)
{
  __shared__ u16 sA[128*136];   // xf -> fx -> t -> fx_next / pool scratch
  __shared__ u16 sB[128*136];   // bu -> xb -> fy -> bu_next
  int tid = threadIdx.x; long g0 = (long)blockIdx.x*128;
  int lane = tid & 63, wid = tid >> 6;
  int g = lane >> 4, c = lane & 15;
  int R0 = wid*32;
  const float* wsc = wsw;
  GLOBAL_TO_LDS128(sB, bub);
  __syncthreads();
  // fwd scans: waves 0,1 on chunks 0,1: sB(bu) -> sA(xf)
  if (wid < 2){
    int p = lane; int cc = wid;
    float Lr = cons[p], Li = cons[64+p];
    long o = ((long)blockIdx.x*2 + cc)*PP + p;
    float xr = wsc[OFF_EF+4*EFS + o], xi = wsc[OFF_EF+5*EFS + o];
    int rb = cc*64;
    #pragma unroll 4
    for (int i=0;i<CHS;i++){
      float br = bf2f(sB[(rb+i)*136+p]), bi = bf2f(sB[(rb+i)*136+64+p]);
      float nr = Lr*xr - Li*xi + br;
      xi = Lr*xi + Li*xr + bi; xr = nr;
      sA[(rb+i)*136+p] = f2bf(xr); sA[(rb+i)*136+64+p] = f2bf(xi);
    }
  }
  __syncthreads();
  ACC_ZERO2(fy0, fy1)
  MAINLOOP2(sA, packy, fy0, fy1, 8, 0);
  __syncthreads();   // sA(xf) fully consumed
  // bwd scans: waves 2,3 IN-PLACE over sB; everyone stages fx -> sA
  if (wid >= 2){
    int p = lane; int cc = wid - 2;
    float Lr = cons[p], Li = cons[64+p];
    long o = ((long)blockIdx.x*2 + cc)*PP + p;
    float yr = wsc[OFF_EF+6*EFS + o], yi = wsc[OFF_EF+7*EFS + o];
    int rb = cc*64;
    #pragma unroll 4
    for (int i=CHS-1;i>=0;i--){
      float br = bf2f(sB[(rb+i)*136+p]), bi = bf2f(sB[(rb+i)*136+64+p]);
      float nr = Lr*yr - Li*yi + br;
      yi = Lr*yi + Li*yr + bi; yr = nr;
      sB[(rb+i)*136+p] = f2bf(yr); sB[(rb+i)*136+64+p] = f2bf(yi);
    }
  }
  GLOBAL_TO_LDS128(sA, fxb);
  __syncthreads();
  MAINLOOP2(sB, packy, fy0, fy1, 8, 4);
  // a = gelu(y + D*fx) + fx
  #define YEPI2(ACC, RT) \
    _Pragma("unroll") for (int ct=0; ct<8; ct++){ int col = ct*16 + c; \
      float dvc = Dv[col]; \
      _Pragma("unroll") for (int q=0;q<4;q++){ \
        int rowL = R0 + (RT)*16 + g*4 + q; \
        float fxv = bf2f(sA[rowL*136 + col]); \
        ACC[ct][q] = gelu_(ACC[ct][q] + dvc*fxv) + fxv; } }
  YEPI2(fy0, 0)
  YEPI2(fy1, 1)
  // LN2 -> fy bf16 into sB own rows
  #define YLN2(ACC, RT) \
    _Pragma("unroll") for (int q=0;q<4;q++){ \
      float sm=0.f, sq=0.f; \
      _Pragma("unroll") for (int ct=0;ct<8;ct++){ float v=ACC[ct][q]; sm+=v; sq+=v*v; } \
      sm += __shfl_xor(sm,1); sq += __shfl_xor(sq,1); \
      sm += __shfl_xor(sm,2); sq += __shfl_xor(sq,2); \
      sm += __shfl_xor(sm,4); sq += __shfl_xor(sq,4); \
      sm += __shfl_xor(sm,8); sq += __shfl_xor(sq,8); \
      float m = sm*(1.0f/HH); \
      float inv = 1.0f/sqrtf(sq*(1.0f/HH) - m*m + 1e-5f); \
      int rowL = R0 + (RT)*16 + g*4 + q; \
      _Pragma("unroll") for (int ct=0;ct<8;ct++){ int col = ct*16 + c; \
        sB[rowL*136 + col] = f2bf((ACC[ct][q]-m)*inv*fg[col] + fb[col]); } }
  YLN2(fy0, 0)
  YLN2(fy1, 1)
  // enc: A-frags from sB(fy) own rows; t -> sA own rows
  bf16x8 af0[4], af1[4];
  #pragma unroll
  for (int ks=0; ks<4; ks++){
    af0[ks] = *(const bf16x8*)&sB[(R0 + c)*136 + ks*32 + g*8];
    af1[ks] = *(const bf16x8*)&sB[(R0 + 16 + c)*136 + ks*32 + g*8];
  }
  #pragma unroll
  for (int ct=0; ct<8; ct++){
    f32x4 z = {0.f,0.f,0.f,0.f};
    f32x4 av0=z, av1=z, ag0=z, ag1=z;
    #pragma unroll
    for (int ks=0; ks<4; ks++){
      bf16x8 bv = ((const bf16x8*)packe)[(ct*4 + ks)*64 + lane];
      bf16x8 bg = ((const bf16x8*)packe)[((ct+8)*4 + ks)*64 + lane];
      av0 = __builtin_amdgcn_mfma_f32_16x16x32_bf16(af0[ks], bv, av0, 0,0,0);
      av1 = __builtin_amdgcn_mfma_f32_16x16x32_bf16(af1[ks], bv, av1, 0,0,0);
      ag0 = __builtin_amdgcn_mfma_f32_16x16x32_bf16(af0[ks], bg, ag0, 0,0,0);
      ag1 = __builtin_amdgcn_mfma_f32_16x16x32_bf16(af1[ks], bg, ag1, 0,0,0);
    }
    #pragma unroll
    for (int q=0;q<4;q++){
      sA[(R0 + g*4 + q)*136 + ct*16 + c]      = f2bf(av0[q]*gelu_(ag0[q]));
      sA[(R0 + 16 + g*4 + q)*136 + ct*16 + c] = f2bf(av1[q]*gelu_(ag1[q]));
    }
  }
  // dec GEMM
  ACC_ZERO2(ad0, ad1)
  MAINLOOP2(sA, packd, ad0, ad1, 4, 0);
  // blk + fy(sB) + h residual; LN3 -> AD (h write deferred to tails)
  #define DADD2(AD, RT) \
    _Pragma("unroll") for (int ct=0; ct<8; ct++){ int col = ct*16 + c; \
      _Pragma("unroll") for (int q=0;q<4;q++){ \
        int rowL = R0 + (RT)*16 + g*4 + q; long ix = (g0+rowL)*HH + col; \
        AD[ct][q] += bf2f(sB[rowL*136 + col]) + h[ix]; } }
  DADD2(ad0, 0)
  DADD2(ad1, 1)
  #define DLN2(AD, RT) \
    _Pragma("unroll") for (int q=0;q<4;q++){ \
      float sm=0.f, sq=0.f; \
      _Pragma("unroll") for (int ct=0;ct<8;ct++){ float v=AD[ct][q]; sm+=v; sq+=v*v; } \
      sm += __shfl_xor(sm,1); sq += __shfl_xor(sq,1); \
      sm += __shfl_xor(sm,2); sq += __shfl_xor(sq,2); \
      sm += __shfl_xor(sm,4); sq += __shfl_xor(sq,4); \
      sm += __shfl_xor(sm,8); sq += __shfl_xor(sq,8); \
      float m = sm*(1.0f/HH); \
      float inv = 1.0f/sqrtf(sq*(1.0f/HH) - m*m + 1e-5f); \
      int rowL = R0 + (RT)*16 + g*4 + q; (void)rowL; \
      _Pragma("unroll") for (int ct=0;ct<8;ct++){ int col = ct*16 + c; \
        AD[ct][q] = (AD[ct][q]-m)*inv*og[col] + ob[col]; } }
  DLN2(ad0, 0)
  DLN2(ad1, 1)
  if (do_tail){
    // write h (needed by next layer's residual)
    #pragma unroll
    for (int ct=0; ct<8; ct++){ int col = ct*16 + c;
      #pragma unroll
      for (int q=0;q<4;q++){
        h[(g0 + R0 + g*4 + q)*HH + col]      = ad0[ct][q];
        h[(g0 + R0 + 16 + g*4 + q)*HH + col] = ad1[ct][q]; } }
    // next-layer LN1 on register h; fx -> sA own rows
    #define TLN(AD, RT) \
      _Pragma("unroll") for (int q=0;q<4;q++){ \
        float sm=0.f, sq=0.f; \
        _Pragma("unroll") for (int ct=0;ct<8;ct++){ float v=AD[ct][q]; sm+=v; sq+=v*v; } \
        sm += __shfl_xor(sm,1); sq += __shfl_xor(sq,1); \
        sm += __shfl_xor(sm,2); sq += __shfl_xor(sq,2); \
        sm += __shfl_xor(sm,4); sq += __shfl_xor(sq,4); \
        sm += __shfl_xor(sm,8); sq += __shfl_xor(sq,8); \
        float m = sm*(1.0f/HH); \
        float inv = 1.0f/sqrtf(sq*(1.0f/HH) - m*m + 1e-5f); \
        int rowL = R0 + (RT)*16 + g*4 + q; \
        _Pragma("unroll") for (int ct=0;ct<8;ct++){ int col = ct*16 + c; \
          sA[rowL*136 + col] = f2bf((AD[ct][q]-m)*inv*gam_nx[col] + bta_nx[col]); } }
    TLN(ad0, 0)
    TLN(ad1, 1)
    __syncthreads();
    LDS_TO_GLOBAL128(sA, (u16*)fxb);
    ACC_ZERO2(bc0, bc1)
    MAINLOOP2(sA, packbu_nx, bc0, bc1, 4, 0);
    #pragma unroll
    for (int ct=0; ct<8; ct++){ int col = ct*16 + c;
      #pragma unroll
      for (int q=0;q<4;q++){
        sB[(R0 + g*4 + q)*136 + col]      = f2bf(bc0[ct][q]);
        sB[(R0 + 16 + g*4 + q)*136 + col] = f2bf(bc1[ct][q]); } }
    __syncthreads();
    LDS_TO_GLOBAL128(sB, (u16*)bub);
    TILE_SCAN_REDUCE(sB, cons_nx, wsw);
  } else {
    // last layer: fused mean-pool partials (skip h write entirely)
    float* sAf = (float*)sA;   // 512-float scratch (sA dead)
    float ps[8];
    #pragma unroll
    for (int ct=0; ct<8; ct++){
      float s8 = 0.f;
      #pragma unroll
      for (int q=0;q<4;q++) s8 += ad0[ct][q] + ad1[ct][q];
      // reduce over g (rows within wave): lanes differ in bits 4-5
      s8 += __shfl_xor(s8, 16);
      s8 += __shfl_xor(s8, 32);
      ps[ct] = s8;   // all lanes now hold wave's 32-row sum for col ct*16+c
    }
    __syncthreads();   // everyone done reading sA as bf16 (dec done earlier)
    if ((lane>>4) == 0){
      #pragma unroll
      for (int ct=0; ct<8; ct++)
        sAf[wid*128 + ct*16 + c] = ps[ct];
    }
    __syncthreads();
    if (tid < 128){
      float tot = sAf[tid] + sAf[128+tid] + sAf[256+tid] + sAf[384+tid];
      wsw[OFF_EF + (long)blockIdx.x*HH + tid] = tot;
    }
  }
}

// ================= classifier head (fp32 out); pooled from per-block partials =================
__global__ void k_cls(const float* __restrict__ part, const float* __restrict__ Wc1,
                      const float* __restrict__ bc1, const float* __restrict__ Wc2,
                      const float* __restrict__ bc2, float* __restrict__ out)
{
  __shared__ float pooled[BB*HH];
  __shared__ float zs[BB*64];
  int tid = threadIdx.x;
  for (int k=0;k<8;k++){
    int e = tid + k*256; int b = e>>7, hh = e&127;
    float s = 0.f;
    for (int seg=0; seg<64; seg++) s += part[((long)b*64 + seg)*HH + hh];
    pooled[e] = s * (1.0f/(float)LL);
  }
  __syncthreads();
  for (int k=0;k<4;k++){
    int e = tid + k*256; int b = e>>6, j = e&63;
    float s = bc1[j];
    for (int hh=0; hh<HH; hh++) s += pooled[b*HH+hh]*Wc1[hh*64+j];
    zs[e] = fmaxf(s, 0.0f);
  }
  __syncthreads();
  if (tid < BB*3){
    int b = tid/3, cc = tid%3;
    float s = bc2[cc];
    for (int j=0;j<64;j++) s += zs[b*64+j]*Wc2[j*3+cc];
    out[tid] = s;
  }
}

extern "C" void kernel_launch(void* const* d_in, const int* in_sizes, int n_in,
                              void* d_out, int out_size, void* d_ws, size_t ws_size,
                              hipStream_t stream) {
  const float* x       = (const float*)d_in[0];
  const float* W_in    = (const float*)d_in[1];
  const float* b_in    = (const float*)d_in[2];
  const float* attn_g  = (const float*)d_in[3];
  const float* attn_b  = (const float*)d_in[4];
  const float* Lam_re  = (const float*)d_in[5];
  const float* Lam_im  = (const float*)d_in[6];
  const float* B_re    = (const float*)d_in[7];
  const float* B_im    = (const float*)d_in[8];
  const float* C_re    = (const float*)d_in[9];
  const float* C_im    = (const float*)d_in[10];
  const float* Dv      = (const float*)d_in[11];
  const float* log_step= (const float*)d_in[12];
  const float* ff_g    = (const float*)d_in[13];
  const float* ff_b    = (const float*)d_in[14];
  const float* W_enc   = (const float*)d_in[15];
  const float* W_dec   = (const float*)d_in[16];
  const float* out_g   = (const float*)d_in[17];
  const float* out_b   = (const float*)d_in[18];
  const float* Wc1     = (const float*)d_in[19];
  const float* bc1     = (const float*)d_in[20];
  const float* Wc2     = (const float*)d_in[21];
  const float* bc2     = (const float*)d_in[22];
  float* ws = (float*)d_ws;

  float* hbuf = ws + OFF_H;
  u16* fxb = (u16*)(ws + OFF_FX);
  u16* bub = (u16*)(ws + OFF_BU);

  k_pre<<<dim3(NLAY,16), 256, 0, stream>>>(Lam_re, Lam_im, B_re, B_im, C_re, C_im,
                                           W_enc, W_dec, log_step, ws);
  k_inproj<<<dim3(LL/256, BB), 256, 0, stream>>>(x, W_in, b_in, hbuf);

  // layer 0 bus
  {
    const u16* pk0 = (const u16*)(ws + OFF_PC);
    const float* cons0 = ws + OFF_PC + 49152;
    k_bus<<<ROWS/128, 256, 0, stream>>>(hbuf, attn_g, attn_b, pk0, fxb, bub, cons0, ws);
  }
  for (int i=0;i<NLAY;i++){
    const u16* pk = (const u16*)(ws + OFF_PC + (unsigned long)i*PCS);
    const float* cons = ws + OFF_PC + (unsigned long)i*PCS + 49152;
    int nx = i+1;
    const u16* pk_nx = (const u16*)(ws + OFF_PC + (unsigned long)(nx % NLAY)*PCS);
    const float* cons_nx = ws + OFF_PC + (unsigned long)(nx % NLAY)*PCS + 49152;
    int do_tail = (nx < NLAY) ? 1 : 0;
    k_scanB<<<dim3(BB,2), 64, 0, stream>>>(cons, ws);
    k_syed<<<ROWS/128, 256, 0, stream>>>(bub, fxb, hbuf, cons, ws,
                                         pk + 16384, pk + 49152, pk + 81920,
                                         Dv+i*HH, ff_g+i*HH, ff_b+i*HH,
                                         out_g+i*HH, out_b+i*HH,
                                         do_tail,
                                         attn_g + (nx % NLAY)*HH, attn_b + (nx % NLAY)*HH,
                                         pk_nx, cons_nx);
  }
  k_cls<<<1, 256, 0, stream>>>(ws + OFF_EF, Wc1, bc1, Wc2, bc2, (float*)d_out);
}

// Round 27
// 332.332 us; speedup vs baseline: 1.1920x; 1.0068x over previous
//
#include <hip/hip_runtime.h>
#include <hip/hip_bf16.h>
#include <math.h>

#define NLAY 2
#define BB 16
#define LL 8192
#define HH 128
#define PP 64
#define CIN 64
#define CHS 64            // scan chunk size; tile = 2 chunks = 128 rows
#define NCH 128           // LL/CHS
#define ROWS (BB*LL)      // 131072

typedef unsigned short u16;
typedef __attribute__((ext_vector_type(8))) short  bf16x8;
typedef __attribute__((ext_vector_type(4))) float  f32x4;

// ---- workspace layout (float offsets) ----
#define OFF_H   0ul               // h fp32 [ROWS][128]
#define OFF_FX  16777216ul        // fx bf16 [ROWS][128]
#define OFF_BU  41943040ul        // bu bf16
#define OFF_EF  50331648ul        // carries at 4..7*EFS; 0..EFS doubles as pool partials (last layer)
#define OFF_PC  51380224ul
#define PCS     49408ul           // per-layer: packs 49152 floats (98304 bf16) + 256 consts
#define EFS     131072ul

// fast gelu: erf via Abramowitz-Stegun 7.1.26 (max err 1.5e-7) + HW exp
__device__ __forceinline__ float gelu_(float x){
  float z = fabsf(x)*0.70710678118654752440f;
  float t = 1.0f/(1.0f + 0.3275911f*z);
  float poly = t*(0.254829592f + t*(-0.284496736f + t*(1.421413741f
             + t*(-1.453152027f + t*1.061405429f))));
  float erfv = 1.0f - poly*__expf(-z*z);
  erfv = copysignf(erfv, x);
  return 0.5f*x*(1.0f + erfv);
}
// bf16 convert via HW instruction (compiler lowers cast to v_cvt_pk_bf16_f32)
__device__ __forceinline__ u16 f2bf(float f){
  __hip_bfloat16 b = __float2bfloat16(f);
  return *reinterpret_cast<u16*>(&b);
}
__device__ __forceinline__ float bf2f(u16 v){
  return __uint_as_float(((unsigned int)v)<<16);
}

// ================= precompute (parallelized: grid (NLAY,16)) =================
__global__ void k_pre(const float* __restrict__ Lam_re, const float* __restrict__ Lam_im,
                      const float* __restrict__ B_re, const float* __restrict__ B_im,
                      const float* __restrict__ C_re, const float* __restrict__ C_im,
                      const float* __restrict__ W_enc, const float* __restrict__ W_dec,
                      const float* __restrict__ log_step, float* __restrict__ ws)
{
  int i = blockIdx.x, sl = blockIdx.y, tid = threadIdx.x;
  float* pcf = ws + OFF_PC + (unsigned long)i*PCS;
  u16* pb = (u16*)pcf;
  float* cons = pcf + 49152;
  __shared__ float qre[PP], qim[PP];
  if (tid < PP){
    int p = tid;
    float lre = Lam_re[i*PP+p], lim = Lam_im[i*PP+p];
    float st = expf(log_step[i*PP+p]);
    float er = expf(lre*st), ang = lim*st;
    float Lr = er*cosf(ang), Li = er*sinf(ang);
    float wr = Lr - 1.0f, wi = Li;
    float den = lre*lre + lim*lim;
    qre[p] = (wr*lre + wi*lim)/den;
    qim[p] = (wi*lre - wr*lim)/den;
    if (sl == 0){
      cons[p] = Lr; cons[64+p] = Li;
      float ec = expf(lre*st*(float)CHS), ac = lim*st*(float)CHS;
      cons[128+p] = ec*cosf(ac); cons[192+p] = ec*sinf(ac);
    }
  }
  __syncthreads();
  // bu pack
  for (int t0 = sl*1024 + tid; t0 < (sl+1)*1024; t0 += 256){
    int j = t0&7, ln = (t0>>3)&63, ks = (t0>>9)&3, ct = t0>>11;
    int col = ct*16 + (ln&15);
    int k = ks*32 + (ln>>4)*8 + j;
    int cc = col>>6, p = col&63;
    float br = B_re[(i*PP+p)*HH + k], bi = B_im[(i*PP+p)*HH + k];
    pb[t0] = f2bf(cc ? (qre[p]*bi + qim[p]*br) : (qre[p]*br - qim[p]*bi));
  }
  // y pack
  for (int t0 = sl*2048 + tid; t0 < (sl+1)*2048; t0 += 256){
    int j = t0&7, ln = (t0>>3)&63, ks = (t0>>9)&7, ct = t0>>12;
    int hh = ct*16 + (ln&15);
    int k = ks*32 + (ln>>4)*8 + j;
    int blk = k>>6, p = k&63;
    int base = (i*HH + hh)*(2*PP);
    float v = (blk==0)? C_re[base+p] : (blk==1)? -C_im[base+p]
            : (blk==2)? C_re[base+PP+p] : -C_im[base+PP+p];
    pb[16384 + t0] = f2bf(v);
  }
  // enc pack
  for (int t0 = sl*2048 + tid; t0 < (sl+1)*2048; t0 += 256){
    int j = t0&7, ln = (t0>>3)&63, ks = (t0>>9)&3, ct = t0>>11;
    int colj = (ct<8) ? ct*16 + (ln&15) : 128 + (ct-8)*16 + (ln&15);
    int k = ks*32 + (ln>>4)*8 + j;
    pb[49152 + t0] = f2bf(W_enc[((long)i*HH + k)*(2*HH) + colj]);
  }
  // dec pack
  for (int t0 = sl*1024 + tid; t0 < (sl+1)*1024; t0 += 256){
    int j = t0&7, ln = (t0>>3)&63, ks = (t0>>9)&3, ct = t0>>11;
    int col = ct*16 + (ln&15);
    int k = ks*32 + (ln>>4)*8 + j;
    pb[81920 + t0] = f2bf(W_dec[((long)i*HH + k)*HH + col]);
  }
}

// ================= input projection (fp32 VALU) =================
#define WRITEOUT32(ARR, COLBASE, DST) \
  __syncthreads(); \
  _Pragma("unroll") \
  for (int jj=0;jj<32;jj++) s[tid*33+jj] = ARR[jj]; \
  __syncthreads(); \
  _Pragma("unroll") \
  for (int k2=0;k2<32;k2++){ int e = tid + k2*256; int r = e>>5, jj = e&31; \
    (DST)[(g0+(long)r)*HH + (COLBASE) + jj] = s[r*33+jj]; }

__global__ __launch_bounds__(256,2) void k_inproj(const float* __restrict__ x,
                         const float* __restrict__ W_in,
                         const float* __restrict__ b_in, float* __restrict__ hout)
{
  __shared__ float s[256*33];
  int tid = threadIdx.x;
  int b = blockIdx.y;
  int l0 = blockIdx.x*256;
  long g0 = (long)b*LL + l0;
  float c0[32], c1[32], c2[32], c3[32];
  #pragma unroll
  for (int j=0;j<32;j++){ c0[j]=b_in[j]; c1[j]=b_in[32+j]; c2[j]=b_in[64+j]; c3[j]=b_in[96+j]; }
  #define INP_CHUNK(KC) { \
    __syncthreads(); \
    _Pragma("unroll") \
    for (int k2=0;k2<32;k2++){ \
      s[tid*33+k2] = x[((long)b*CIN + (KC)*32+k2)*LL + l0 + tid]; } \
    __syncthreads(); \
    _Pragma("unroll 2") \
    for (int kk=0;kk<32;kk++){ \
      float a = s[tid*33+kk]; \
      const float* wr = W_in + ((KC)*32+kk)*HH; \
      _Pragma("unroll") \
      for (int j=0;j<32;j++){ c0[j]+=a*wr[j]; c1[j]+=a*wr[32+j]; c2[j]+=a*wr[64+j]; c3[j]+=a*wr[96+j]; } \
    } }
  INP_CHUNK(0) INP_CHUNK(1)
  WRITEOUT32(c0, 0, hout)
  WRITEOUT32(c1, 32, hout)
  WRITEOUT32(c2, 64, hout)
  WRITEOUT32(c3, 96, hout)
}

// ================= helpers for 128-row tiles =================
#define LDS_TO_GLOBAL128(SRCLDS, DST) do{ \
  _Pragma("unroll") \
  for (int rep=0; rep<8; rep++){ int e = tid + rep*256; \
    int r = e>>4, c8 = (e&15)*8; \
    *(bf16x8*)((DST) + (g0 + r)*HH + c8) = *(const bf16x8*)&(SRCLDS)[r*136 + c8]; } }while(0)

#define GLOBAL_TO_LDS128(DSTLDS, SRC) do{ \
  _Pragma("unroll") \
  for (int rep=0; rep<8; rep++){ int e = tid + rep*256; \
    int r = e>>4, c8 = (e&15)*8; \
    *(bf16x8*)&(DSTLDS)[r*136 + c8] = *(const bf16x8*)((SRC) + (g0 + r)*HH + c8); } }while(0)

// two row-tiles per wave: rows R0+c and R0+16+c
#define MAINLOOP2(LDSA, PACK, ACCA, ACCB, KSTOT, KSOFF) do{ \
  _Pragma("unroll") \
  for (int ks=0; ks<4; ks++){ \
    bf16x8 a0 = *(const bf16x8*)&(LDSA)[(R0 + c)*136 + ks*32 + g*8]; \
    bf16x8 a1 = *(const bf16x8*)&(LDSA)[(R0 + 16 + c)*136 + ks*32 + g*8]; \
    _Pragma("unroll") \
    for (int ct=0; ct<8; ct++){ \
      bf16x8 b = ((const bf16x8*)(PACK))[(ct*(KSTOT) + (KSOFF) + ks)*64 + lane]; \
      ACCA[ct] = __builtin_amdgcn_mfma_f32_16x16x32_bf16(a0, b, ACCA[ct], 0,0,0); \
      ACCB[ct] = __builtin_amdgcn_mfma_f32_16x16x32_bf16(a1, b, ACCB[ct], 0,0,0); } } }while(0)

#define ACC_ZERO2(ACCA, ACCB) \
  f32x4 ACCA[8], ACCB[8]; \
  { f32x4 z = {0.f,0.f,0.f,0.f}; \
    _Pragma("unroll") for (int ct=0; ct<8; ct++){ ACCA[ct]=z; ACCB[ct]=z; } }

// scan reductions from a 128x136 LDS bu tile (all 4 waves: dir=w>>1, chunk=w&1)
#define TILE_SCAN_REDUCE(SB, CONS, WS) do{ \
  int p = lane; int cc = wid & 1; \
  long o = ((long)blockIdx.x*2 + cc)*PP + p; \
  float Lr = (CONS)[p], Li = (CONS)[64+p]; \
  int rb = cc*64; \
  if ((wid>>1) == 0){ \
    float efr=0.f, efi=0.f; \
    _Pragma("unroll 4") \
    for (int i=0;i<CHS;i++){ \
      float br = bf2f((SB)[(rb+i)*136+p]), bi = bf2f((SB)[(rb+i)*136+64+p]); \
      float nr = Lr*efr - Li*efi + br; \
      efi = Lr*efi + Li*efr + bi; efr = nr; \
    } \
    (WS)[OFF_EF + o] = efr;  (WS)[OFF_EF+EFS + o] = efi; \
  } else { \
    float ebr=0.f, ebi=0.f, pwr=1.f, pwi=0.f; \
    _Pragma("unroll 4") \
    for (int i=0;i<CHS;i++){ \
      float br = bf2f((SB)[(rb+i)*136+p]), bi = bf2f((SB)[(rb+i)*136+64+p]); \
      ebr += pwr*br - pwi*bi; \
      ebi += pwr*bi + pwi*br; \
      float tr = pwr*Lr - pwi*Li; \
      pwi = pwr*Li + pwi*Lr; pwr = tr; \
    } \
    (WS)[OFF_EF+2*EFS + o] = ebr;  (WS)[OFF_EF+3*EFS + o] = ebi; \
  } }while(0)

// ================= k_bus: LN1 + bu GEMM + chunk scan reductions (layer 0 only) =================
__global__ __launch_bounds__(256,2) void k_bus(const float* __restrict__ h,
                      const float* __restrict__ gam, const float* __restrict__ bta,
                      const u16* __restrict__ pack, u16* __restrict__ fxb,
                      u16* __restrict__ bub, const float* __restrict__ cons,
                      float* __restrict__ ws)
{
  __shared__ u16 sA[128*136];   // fx bf16
  __shared__ u16 sB[128*136];   // bu bf16
  int tid = threadIdx.x; long g0 = (long)blockIdx.x*128;
  int lane = tid & 63, wid = tid >> 6;
  int g = lane >> 4, c = lane & 15;
  int R0 = wid*32;
  #pragma unroll
  for (int rr=0; rr<2; rr++){
    int r = rr*64 + (tid>>2), seg = tid&3;
    float hv[32];
    const float* hp = h + (g0 + r)*HH + seg*32;
    #pragma unroll
    for (int j4=0;j4<8;j4++) *(float4*)&hv[j4*4] = *(const float4*)(hp + j4*4);
    float sum=0.f, sq=0.f;
    #pragma unroll
    for (int j=0;j<32;j++){ sum += hv[j]; sq += hv[j]*hv[j]; }
    sum += __shfl_xor(sum,1); sq += __shfl_xor(sq,1);
    sum += __shfl_xor(sum,2); sq += __shfl_xor(sq,2);
    float m = sum*(1.0f/HH);
    float inv = 1.0f/sqrtf(sq*(1.0f/HH) - m*m + 1e-5f);
    #pragma unroll
    for (int j=0;j<32;j++){
      int col = seg*32 + j;
      sA[r*136 + col] = f2bf((hv[j]-m)*inv*gam[col] + bta[col]);
    }
  }
  __syncthreads();
  LDS_TO_GLOBAL128(sA, fxb);
  ACC_ZERO2(acc0, acc1)
  MAINLOOP2(sA, pack, acc0, acc1, 4, 0);
  #pragma unroll
  for (int ct=0; ct<8; ct++){ int col = ct*16 + c;
    #pragma unroll
    for (int q=0;q<4;q++){
      sB[(R0 + g*4 + q)*136 + col]      = f2bf(acc0[ct][q]);
      sB[(R0 + 16 + g*4 + q)*136 + col] = f2bf(acc1[ct][q]); } }
  __syncthreads();
  LDS_TO_GLOBAL128(sB, bub);
  TILE_SCAN_REDUCE(sB, cons, ws);
}

// ================= scan B: carry scan over chunks =================
__global__ void k_scanB(const float* __restrict__ cons, float* __restrict__ ws)
{
  __shared__ float sr[NCH*PP], si[NCH*PP];
  int p = threadIdx.x; int b = blockIdx.x, dir = blockIdx.y;
  float Cr = cons[128+p], Ci = cons[192+p];
  long base = (long)b*NCH*PP;
  const float* er_g = ws + OFF_EF + (dir ? 2*EFS : 0ul)  + base;
  const float* ei_g = ws + OFF_EF + (dir ? 3*EFS : EFS)  + base;
  #pragma unroll 4
  for (int ch=0; ch<NCH; ch++){
    sr[ch*PP+p] = er_g[ch*PP+p];
    si[ch*PP+p] = ei_g[ch*PP+p];
  }
  if (dir == 0){
    float Fr=0.f, Fi=0.f;
    float* or_g = ws + OFF_EF + 4*EFS + base;
    float* oi_g = ws + OFF_EF + 5*EFS + base;
    for (int ch=0; ch<NCH; ch++){
      or_g[ch*PP+p] = Fr; oi_g[ch*PP+p] = Fi;
      float er = sr[ch*PP+p], ei = si[ch*PP+p];
      float nr = Cr*Fr - Ci*Fi + er;
      Fi = Cr*Fi + Ci*Fr + ei; Fr = nr;
    }
  } else {
    float Xr=0.f, Xi=0.f;
    float* or_g = ws + OFF_EF + 6*EFS + base;
    float* oi_g = ws + OFF_EF + 7*EFS + base;
    for (int ch=NCH-1; ch>=0; ch--){
      or_g[ch*PP+p] = Xr; oi_g[ch*PP+p] = Xi;
      float er = sr[ch*PP+p], ei = si[ch*PP+p];
      float nr = er + Cr*Xr - Ci*Xi;
      Xi = ei + Cr*Xi + Ci*Xr; Xr = nr;
    }
  }
}

// ================= fused k_syed (+ tail: next-layer bus OR pooling) =================
__global__ __launch_bounds__(256,2) void k_syed(const u16* __restrict__ bub,
                      const u16* __restrict__ fxb, float* __restrict__ h,
                      const float* __restrict__ cons, float* __restrict__ wsw,
                      const u16* __restrict__ packy, const u16* __restrict__ packe,
                      const u16* __restrict__ packd,
                      const float* __restrict__ Dv,
                      const float* __restrict__ fg, const float* __restrict__ fb,
                      const float* __restrict__ og, const float* __restrict__ ob,
                      int do_tail,
                      const float* __restrict__ gam_nx, const float* __restrict__ bta_nx,
                      const u16* __restrict__ packbu_nx, const float* __restrict__ cons_nx)
{
  __shared__ u16 sA[128*136];   // xf -> fx -> t -> fx_next / pool scratch
  __shared__ u16 sB[128*136];   // bu -> xb -> fy -> bu_next
  int tid = threadIdx.x; long g0 = (long)blockIdx.x*128;
  int lane = tid & 63, wid = tid >> 6;
  int g = lane >> 4, c = lane & 15;
  int R0 = wid*32;
  const float* wsc = wsw;
  GLOBAL_TO_LDS128(sB, bub);
  __syncthreads();
  // fwd scans: waves 0,1 on chunks 0,1: sB(bu) -> sA(xf)
  if (wid < 2){
    int p = lane; int cc = wid;
    float Lr = cons[p], Li = cons[64+p];
    long o = ((long)blockIdx.x*2 + cc)*PP + p;
    float xr = wsc[OFF_EF+4*EFS + o], xi = wsc[OFF_EF+5*EFS + o];
    int rb = cc*64;
    #pragma unroll 4
    for (int i=0;i<CHS;i++){
      float br = bf2f(sB[(rb+i)*136+p]), bi = bf2f(sB[(rb+i)*136+64+p]);
      float nr = Lr*xr - Li*xi + br;
      xi = Lr*xi + Li*xr + bi; xr = nr;
      sA[(rb+i)*136+p] = f2bf(xr); sA[(rb+i)*136+64+p] = f2bf(xi);
    }
  }
  __syncthreads();
  ACC_ZERO2(fy0, fy1)
  MAINLOOP2(sA, packy, fy0, fy1, 8, 0);
  __syncthreads();   // sA(xf) fully consumed
  // bwd scans: waves 2,3 IN-PLACE over sB; everyone stages fx -> sA
  if (wid >= 2){
    int p = lane; int cc = wid - 2;
    float Lr = cons[p], Li = cons[64+p];
    long o = ((long)blockIdx.x*2 + cc)*PP + p;
    float yr = wsc[OFF_EF+6*EFS + o], yi = wsc[OFF_EF+7*EFS + o];
    int rb = cc*64;
    #pragma unroll 4
    for (int i=CHS-1;i>=0;i--){
      float br = bf2f(sB[(rb+i)*136+p]), bi = bf2f(sB[(rb+i)*136+64+p]);
      float nr = Lr*yr - Li*yi + br;
      yi = Lr*yi + Li*yr + bi; yr = nr;
      sB[(rb+i)*136+p] = f2bf(yr); sB[(rb+i)*136+64+p] = f2bf(yi);
    }
  }
  GLOBAL_TO_LDS128(sA, fxb);
  __syncthreads();
  MAINLOOP2(sB, packy, fy0, fy1, 8, 4);
  // a = gelu(y + D*fx) + fx
  #define YEPI2(ACC, RT) \
    _Pragma("unroll") for (int ct=0; ct<8; ct++){ int col = ct*16 + c; \
      float dvc = Dv[col]; \
      _Pragma("unroll") for (int q=0;q<4;q++){ \
        int rowL = R0 + (RT)*16 + g*4 + q; \
        float fxv = bf2f(sA[rowL*136 + col]); \
        ACC[ct][q] = gelu_(ACC[ct][q] + dvc*fxv) + fxv; } }
  YEPI2(fy0, 0)
  YEPI2(fy1, 1)
  // LN2 -> fy bf16 into sB own rows
  #define YLN2(ACC, RT) \
    _Pragma("unroll") for (int q=0;q<4;q++){ \
      float sm=0.f, sq=0.f; \
      _Pragma("unroll") for (int ct=0;ct<8;ct++){ float v=ACC[ct][q]; sm+=v; sq+=v*v; } \
      sm += __shfl_xor(sm,1); sq += __shfl_xor(sq,1); \
      sm += __shfl_xor(sm,2); sq += __shfl_xor(sq,2); \
      sm += __shfl_xor(sm,4); sq += __shfl_xor(sq,4); \
      sm += __shfl_xor(sm,8); sq += __shfl_xor(sq,8); \
      float m = sm*(1.0f/HH); \
      float inv = 1.0f/sqrtf(sq*(1.0f/HH) - m*m + 1e-5f); \
      int rowL = R0 + (RT)*16 + g*4 + q; \
      _Pragma("unroll") for (int ct=0;ct<8;ct++){ int col = ct*16 + c; \
        sB[rowL*136 + col] = f2bf((ACC[ct][q]-m)*inv*fg[col] + fb[col]); } }
  YLN2(fy0, 0)
  YLN2(fy1, 1)
  // enc: A-frags from sB(fy) own rows; t -> sA own rows
  bf16x8 af0[4], af1[4];
  #pragma unroll
  for (int ks=0; ks<4; ks++){
    af0[ks] = *(const bf16x8*)&sB[(R0 + c)*136 + ks*32 + g*8];
    af1[ks] = *(const bf16x8*)&sB[(R0 + 16 + c)*136 + ks*32 + g*8];
  }
  #pragma unroll
  for (int ct=0; ct<8; ct++){
    f32x4 z = {0.f,0.f,0.f,0.f};
    f32x4 av0=z, av1=z, ag0=z, ag1=z;
    #pragma unroll
    for (int ks=0; ks<4; ks++){
      bf16x8 bv = ((const bf16x8*)packe)[(ct*4 + ks)*64 + lane];
      bf16x8 bg = ((const bf16x8*)packe)[((ct+8)*4 + ks)*64 + lane];
      av0 = __builtin_amdgcn_mfma_f32_16x16x32_bf16(af0[ks], bv, av0, 0,0,0);
      av1 = __builtin_amdgcn_mfma_f32_16x16x32_bf16(af1[ks], bv, av1, 0,0,0);
      ag0 = __builtin_amdgcn_mfma_f32_16x16x32_bf16(af0[ks], bg, ag0, 0,0,0);
      ag1 = __builtin_amdgcn_mfma_f32_16x16x32_bf16(af1[ks], bg, ag1, 0,0,0);
    }
    #pragma unroll
    for (int q=0;q<4;q++){
      sA[(R0 + g*4 + q)*136 + ct*16 + c]      = f2bf(av0[q]*gelu_(ag0[q]));
      sA[(R0 + 16 + g*4 + q)*136 + ct*16 + c] = f2bf(av1[q]*gelu_(ag1[q]));
    }
  }
  // dec GEMM
  ACC_ZERO2(ad0, ad1)
  MAINLOOP2(sA, packd, ad0, ad1, 4, 0);
  // blk + fy(sB) + h residual; LN3 -> AD (h write deferred to tails)
  #define DADD2(AD, RT) \
    _Pragma("unroll") for (int ct=0; ct<8; ct++){ int col = ct*16 + c; \
      _Pragma("unroll") for (int q=0;q<4;q++){ \
        int rowL = R0 + (RT)*16 + g*4 + q; long ix = (g0+rowL)*HH + col; \
        AD[ct][q] += bf2f(sB[rowL*136 + col]) + h[ix]; } }
  DADD2(ad0, 0)
  DADD2(ad1, 1)
  #define DLN2(AD, RT) \
    _Pragma("unroll") for (int q=0;q<4;q++){ \
      float sm=0.f, sq=0.f; \
      _Pragma("unroll") for (int ct=0;ct<8;ct++){ float v=AD[ct][q]; sm+=v; sq+=v*v; } \
      sm += __shfl_xor(sm,1); sq += __shfl_xor(sq,1); \
      sm += __shfl_xor(sm,2); sq += __shfl_xor(sq,2); \
      sm += __shfl_xor(sm,4); sq += __shfl_xor(sq,4); \
      sm += __shfl_xor(sm,8); sq += __shfl_xor(sq,8); \
      float m = sm*(1.0f/HH); \
      float inv = 1.0f/sqrtf(sq*(1.0f/HH) - m*m + 1e-5f); \
      int rowL = R0 + (RT)*16 + g*4 + q; (void)rowL; \
      _Pragma("unroll") for (int ct=0;ct<8;ct++){ int col = ct*16 + c; \
        AD[ct][q] = (AD[ct][q]-m)*inv*og[col] + ob[col]; } }
  DLN2(ad0, 0)
  DLN2(ad1, 1)
  if (do_tail){
    // write h (needed by next layer's residual)
    #pragma unroll
    for (int ct=0; ct<8; ct++){ int col = ct*16 + c;
      #pragma unroll
      for (int q=0;q<4;q++){
        h[(g0 + R0 + g*4 + q)*HH + col]      = ad0[ct][q];
        h[(g0 + R0 + 16 + g*4 + q)*HH + col] = ad1[ct][q]; } }
    // next-layer LN1 on register h; fx -> sA own rows
    #define TLN(AD, RT) \
      _Pragma("unroll") for (int q=0;q<4;q++){ \
        float sm=0.f, sq=0.f; \
        _Pragma("unroll") for (int ct=0;ct<8;ct++){ float v=AD[ct][q]; sm+=v; sq+=v*v; } \
        sm += __shfl_xor(sm,1); sq += __shfl_xor(sq,1); \
        sm += __shfl_xor(sm,2); sq += __shfl_xor(sq,2); \
        sm += __shfl_xor(sm,4); sq += __shfl_xor(sq,4); \
        sm += __shfl_xor(sm,8); sq += __shfl_xor(sq,8); \
        float m = sm*(1.0f/HH); \
        float inv = 1.0f/sqrtf(sq*(1.0f/HH) - m*m + 1e-5f); \
        int rowL = R0 + (RT)*16 + g*4 + q; \
        _Pragma("unroll") for (int ct=0;ct<8;ct++){ int col = ct*16 + c; \
          sA[rowL*136 + col] = f2bf((AD[ct][q]-m)*inv*gam_nx[col] + bta_nx[col]); } }
    TLN(ad0, 0)
    TLN(ad1, 1)
    __syncthreads();
    LDS_TO_GLOBAL128(sA, (u16*)fxb);
    ACC_ZERO2(bc0, bc1)
    MAINLOOP2(sA, packbu_nx, bc0, bc1, 4, 0);
    #pragma unroll
    for (int ct=0; ct<8; ct++){ int col = ct*16 + c;
      #pragma unroll
      for (int q=0;q<4;q++){
        sB[(R0 + g*4 + q)*136 + col]      = f2bf(bc0[ct][q]);
        sB[(R0 + 16 + g*4 + q)*136 + col] = f2bf(bc1[ct][q]); } }
    __syncthreads();
    LDS_TO_GLOBAL128(sB, (u16*)bub);
    TILE_SCAN_REDUCE(sB, cons_nx, wsw);
  } else {
    // last layer: fused mean-pool partials (skip h write entirely)
    float* sAf = (float*)sA;   // 512-float scratch (sA dead)
    float ps[8];
    #pragma unroll
    for (int ct=0; ct<8; ct++){
      float s8 = 0.f;
      #pragma unroll
      for (int q=0;q<4;q++) s8 += ad0[ct][q] + ad1[ct][q];
      // reduce over g (rows within wave): lanes differ in bits 4-5
      s8 += __shfl_xor(s8, 16);
      s8 += __shfl_xor(s8, 32);
      ps[ct] = s8;   // all lanes now hold wave's 32-row sum for col ct*16+c
    }
    __syncthreads();   // everyone done reading sA as bf16 (dec done earlier)
    if ((lane>>4) == 0){
      #pragma unroll
      for (int ct=0; ct<8; ct++)
        sAf[wid*128 + ct*16 + c] = ps[ct];
    }
    __syncthreads();
    if (tid < 128){
      float tot = sAf[tid] + sAf[128+tid] + sAf[256+tid] + sAf[384+tid];
      wsw[OFF_EF + (long)blockIdx.x*HH + tid] = tot;
    }
  }
}

// ================= classifier head (fp32 out); pooled from per-block partials =================
__global__ void k_cls(const float* __restrict__ part, const float* __restrict__ Wc1,
                      const float* __restrict__ bc1, const float* __restrict__ Wc2,
                      const float* __restrict__ bc2, float* __restrict__ out)
{
  __shared__ float pooled[BB*HH];
  __shared__ float zs[BB*64];
  int tid = threadIdx.x;
  for (int k=0;k<8;k++){
    int e = tid + k*256; int b = e>>7, hh = e&127;
    float s = 0.f;
    for (int seg=0; seg<64; seg++) s += part[((long)b*64 + seg)*HH + hh];
    pooled[e] = s * (1.0f/(float)LL);
  }
  __syncthreads();
  for (int k=0;k<4;k++){
    int e = tid + k*256; int b = e>>6, j = e&63;
    float s = bc1[j];
    for (int hh=0; hh<HH; hh++) s += pooled[b*HH+hh]*Wc1[hh*64+j];
    zs[e] = fmaxf(s, 0.0f);
  }
  __syncthreads();
  if (tid < BB*3){
    int b = tid/3, cc = tid%3;
    float s = bc2[cc];
    for (int j=0;j<64;j++) s += zs[b*64+j]*Wc2[j*3+cc];
    out[tid] = s;
  }
}

extern "C" void kernel_launch(void* const* d_in, const int* in_sizes, int n_in,
                              void* d_out, int out_size, void* d_ws, size_t ws_size,
                              hipStream_t stream) {
  const float* x       = (const float*)d_in[0];
  const float* W_in    = (const float*)d_in[1];
  const float* b_in    = (const float*)d_in[2];
  const float* attn_g  = (const float*)d_in[3];
  const float* attn_b  = (const float*)d_in[4];
  const float* Lam_re  = (const float*)d_in[5];
  const float* Lam_im  = (const float*)d_in[6];
  const float* B_re    = (const float*)d_in[7];
  const float* B_im    = (const float*)d_in[8];
  const float* C_re    = (const float*)d_in[9];
  const float* C_im    = (const float*)d_in[10];
  const float* Dv      = (const float*)d_in[11];
  const float* log_step= (const float*)d_in[12];
  const float* ff_g    = (const float*)d_in[13];
  const float* ff_b    = (const float*)d_in[14];
  const float* W_enc   = (const float*)d_in[15];
  const float* W_dec   = (const float*)d_in[16];
  const float* out_g   = (const float*)d_in[17];
  const float* out_b   = (const float*)d_in[18];
  const float* Wc1     = (const float*)d_in[19];
  const float* bc1     = (const float*)d_in[20];
  const float* Wc2     = (const float*)d_in[21];
  const float* bc2     = (const float*)d_in[22];
  float* ws = (float*)d_ws;

  float* hbuf = ws + OFF_H;
  u16* fxb = (u16*)(ws + OFF_FX);
  u16* bub = (u16*)(ws + OFF_BU);

  k_pre<<<dim3(NLAY,16), 256, 0, stream>>>(Lam_re, Lam_im, B_re, B_im, C_re, C_im,
                                           W_enc, W_dec, log_step, ws);
  k_inproj<<<dim3(LL/256, BB), 256, 0, stream>>>(x, W_in, b_in, hbuf);

  // layer 0 bus
  {
    const u16* pk0 = (const u16*)(ws + OFF_PC);
    const float* cons0 = ws + OFF_PC + 49152;
    k_bus<<<ROWS/128, 256, 0, stream>>>(hbuf, attn_g, attn_b, pk0, fxb, bub, cons0, ws);
  }
  for (int i=0;i<NLAY;i++){
    const u16* pk = (const u16*)(ws + OFF_PC + (unsigned long)i*PCS);
    const float* cons = ws + OFF_PC + (unsigned long)i*PCS + 49152;
    int nx = i+1;
    const u16* pk_nx = (const u16*)(ws + OFF_PC + (unsigned long)(nx % NLAY)*PCS);
    const float* cons_nx = ws + OFF_PC + (unsigned long)(nx % NLAY)*PCS + 49152;
    int do_tail = (nx < NLAY) ? 1 : 0;
    k_scanB<<<dim3(BB,2), 64, 0, stream>>>(cons, ws);
    k_syed<<<ROWS/128, 256, 0, stream>>>(bub, fxb, hbuf, cons, ws,
                                         pk + 16384, pk + 49152, pk + 81920,
                                         Dv+i*HH, ff_g+i*HH, ff_b+i*HH,
                                         out_g+i*HH, out_b+i*HH,
                                         do_tail,
                                         attn_g + (nx % NLAY)*HH, attn_b + (nx % NLAY)*HH,
                                         pk_nx, cons_nx);
  }
  k_cls<<<1, 256, 0, stream>>>(ws + OFF_EF, Wc1, bc1, Wc2, bc2, (float*)d_out);
}